// Round 2
// baseline (1306.455 us; speedup 1.0000x reference)
//
#include <hip/hip_runtime.h>
#include <hip/hip_bf16.h>

#define HDIM 512
#define TILE 64
#define TPB 512

typedef __attribute__((ext_vector_type(8))) short short8;
typedef __attribute__((ext_vector_type(4))) float f32x4;

__device__ __forceinline__ unsigned short f2bf(float x) {
  unsigned u = __float_as_uint(x);
  u = (u + 0x7fffu + ((u >> 16) & 1u)) >> 16;   // RNE
  return (unsigned short)u;
}
__device__ __forceinline__ float bf2f(unsigned short h) {
  return __uint_as_float(((unsigned)h) << 16);
}
// XOR-swizzled ushort index into [row][col] bf16 tile, row stride 512 elems.
// x(row) chosen so b128 reads (rows 0..15 per quarter-col) stay even AND
// b16 epilogue stores (rows {r,r+4,r+8,r+12} per quarter) hit 4 distinct
// banksets -> 2-way (free) instead of 4-way.
__device__ __forceinline__ int swz(int row, int col) {
  int xb = ((row >> 2) & 3) | ((row & 1) << 2);
  return (((row << 10) + (col << 1)) ^ (xb << 4)) >> 1;
}

// W2 (512x512 f32 [k][n]) -> bf16 MFMA-fragment-major, fwd B[k][n] and bwd B[n][k].
__global__ void prep_weights(const float* __restrict__ pW2, const float* __restrict__ tW2,
                             unsigned short* __restrict__ pWf, unsigned short* __restrict__ pWb,
                             unsigned short* __restrict__ tWf, unsigned short* __restrict__ tWb) {
  int i = blockIdx.x * blockDim.x + threadIdx.x;
  if (i >= HDIM * HDIM) return;
  int j  = i & 7;
  int l  = (i >> 3) & 63;
  int kb = (i >> 9) & 15;
  int nb = i >> 13;
  int kpos = kb * 32 + ((l >> 4) << 3) + j;
  int npos = nb * 16 + (l & 15);
  pWf[i] = f2bf(pW2[kpos * HDIM + npos]);
  pWb[i] = f2bf(pW2[npos * HDIM + kpos]);
  tWf[i] = f2bf(tW2[kpos * HDIM + npos]);
  tWb[i] = f2bf(tW2[npos * HDIM + kpos]);
}

template <int ARITY>
__global__ void __launch_bounds__(TPB, 4)
energy_kernel(const float* __restrict__ x, const float* __restrict__ sigp,
              const int* __restrict__ edges, int Etot,
              const float* __restrict__ W1, const float* __restrict__ b1,
              const unsigned short* __restrict__ Wf, const unsigned short* __restrict__ Wb,
              const float* __restrict__ b2, const float* __restrict__ w3,
              const float* __restrict__ b3p, float* __restrict__ out) {
  constexpr int IN = 3 * ARITY;   // arity*dim + arity
  constexpr int GD = 2 * ARITY;   // grad components per edge
  __shared__ __align__(16) unsigned short bufA[TILE * HDIM];  // h1 -> dz2 -> dz1
  __shared__ __align__(16) unsigned short W1s[GD * HDIM];     // bf16 W1 rows 0..GD-1 (phase-5 B)
  __shared__ __align__(16) float h0s[TILE][16];
  __shared__ float dh0s[TILE][8];
  __shared__ int   idxs[TILE * ARITY];
  __shared__ float blockE;

  const int tid  = threadIdx.x;
  const int lane = tid & 63;
  const int w    = tid >> 6;
  const int q    = lane >> 4;
  const int lm   = lane & 15;
  const int tile0 = blockIdx.x * TILE;
  const int vcnt  = min(TILE, Etot - tile0);
  const float sigma = sigp[0];

  // ---- phase 0: init ----
  if (tid == 0) blockE = 0.f;
  ((float*)dh0s)[tid] = 0.f;                       // 64*8 == TPB
  if (tid < TILE * ARITY) {
    int e = tid / ARITY;
    idxs[tid] = (e < vcnt) ? edges[(size_t)tile0 * ARITY + tid] : 0;
  }
  for (int i = tid; i < GD * HDIM; i += TPB) W1s[i] = f2bf(W1[i]);
  __syncthreads();
  if (tid < TILE) {
#pragma unroll
    for (int k = 0; k < 16; ++k) h0s[tid][k] = 0.f;
    if (tid < vcnt) {
#pragma unroll
      for (int o = 0; o < ARITY; ++o) {
        int id = idxs[tid * ARITY + o];
        h0s[tid][o * 2 + 0] = x[id * 2 + 0];
        h0s[tid][o * 2 + 1] = x[id * 2 + 1];
        h0s[tid][ARITY * 2 + o] = sigma;
      }
    }
  }
  __syncthreads();

  const int n0 = w * 64;

  // ---- phase 1: layer 1 via split-bf16 MFMA ----
  // A-fragments of h0 (hi/lo), Ah kept live for phase-4 re-MFMA.
  short8 Ah[4], Al[4];
#pragma unroll
  for (int mf = 0; mf < 4; ++mf) {
    f32x4 v0 = {0.f, 0.f, 0.f, 0.f}, v1 = {0.f, 0.f, 0.f, 0.f};
    if (q < 2) {
      const float* p = &h0s[mf * 16 + lm][q * 8];
      v0 = *(const f32x4*)p;
      v1 = *(const f32x4*)(p + 4);
    }
#pragma unroll
    for (int j = 0; j < 4; ++j) {
      unsigned short ha = f2bf(v0[j]);
      Ah[mf][j] = (short)ha;
      Al[mf][j] = (short)f2bf(v0[j] - bf2f(ha));
      unsigned short hb = f2bf(v1[j]);
      Ah[mf][j + 4] = (short)hb;
      Al[mf][j + 4] = (short)f2bf(v1[j] - bf2f(hb));
    }
  }

  f32x4 acc[4][4];
#pragma unroll
  for (int mf = 0; mf < 4; ++mf)
#pragma unroll
    for (int nf = 0; nf < 4; ++nf) acc[mf][nf] = (f32x4){0.f, 0.f, 0.f, 0.f};

  float b1v[4];
#pragma unroll
  for (int nf = 0; nf < 4; ++nf) {
    const int col = n0 + nf * 16 + lm;
    b1v[nf] = b1[col];
    short8 Bh, Bl;
#pragma unroll
    for (int j = 0; j < 8; ++j) {
      int k = q * 8 + j;
      float v = (k < IN) ? W1[k * HDIM + col] : 0.f;
      unsigned short hb = f2bf(v);
      Bh[j] = (short)hb;
      Bl[j] = (short)f2bf(v - bf2f(hb));
    }
#pragma unroll
    for (int mf = 0; mf < 4; ++mf) {
      acc[mf][nf] = __builtin_amdgcn_mfma_f32_16x16x32_bf16(Ah[mf], Bh, acc[mf][nf], 0, 0, 0);
      acc[mf][nf] = __builtin_amdgcn_mfma_f32_16x16x32_bf16(Al[mf], Bh, acc[mf][nf], 0, 0, 0);
      acc[mf][nf] = __builtin_amdgcn_mfma_f32_16x16x32_bf16(Ah[mf], Bl, acc[mf][nf], 0, 0, 0);
    }
  }

  // silu(z1) -> bufA (bf16)
#pragma unroll
  for (int mf = 0; mf < 4; ++mf)
#pragma unroll
    for (int nf = 0; nf < 4; ++nf)
#pragma unroll
      for (int r = 0; r < 4; ++r) {
        int row = mf * 16 + q * 4 + r;
        float z = acc[mf][nf][r] + b1v[nf];
        float s = 1.f / (1.f + __expf(-z));
        float hv = (row < vcnt) ? z * s : 0.f;
        bufA[swz(row, n0 + nf * 16 + lm)] = f2bf(hv);
      }
  __syncthreads();

  float b2v[4], w3v[4];
#pragma unroll
  for (int nf = 0; nf < 4; ++nf) {
    b2v[nf] = b2[n0 + nf * 16 + lm];
    w3v[nf] = w3[n0 + nf * 16 + lm];
  }

  // ---- phase 2: forward GEMM z2 = h1 @ W2 ----
#pragma unroll
  for (int mf = 0; mf < 4; ++mf)
#pragma unroll
    for (int nf = 0; nf < 4; ++nf) acc[mf][nf] = (f32x4){0.f, 0.f, 0.f, 0.f};

#pragma unroll 4
  for (int kk = 0; kk < 16; ++kk) {
    short8 a[4];
#pragma unroll
    for (int mf = 0; mf < 4; ++mf)
      a[mf] = *(const short8*)&bufA[swz(mf * 16 + lm, kk * 32 + q * 8)];
#pragma unroll
    for (int nf = 0; nf < 4; ++nf) {
      short8 bfr = *(const short8*)(Wf + ((((w * 4 + nf) * 16 + kk) * 64 + lane) << 3));
#pragma unroll
      for (int mf = 0; mf < 4; ++mf)
        acc[mf][nf] = __builtin_amdgcn_mfma_f32_16x16x32_bf16(a[mf], bfr, acc[mf][nf], 0, 0, 0);
    }
  }

  // ---- epilogue fwd: energy + dz2 = w3*silu'(z2) ----
  float epart = 0.f;
#pragma unroll
  for (int mf = 0; mf < 4; ++mf)
#pragma unroll
    for (int r = 0; r < 4; ++r) {
      int row = mf * 16 + q * 4 + r;
      bool val = row < vcnt;
#pragma unroll
      for (int nf = 0; nf < 4; ++nf) {
        float z = acc[mf][nf][r] + b2v[nf];
        float s = 1.f / (1.f + __expf(-z));
        float h2 = z * s;
        float sp = s * (1.f + z * (1.f - s));
        epart += val ? h2 * w3v[nf] : 0.f;
        acc[mf][nf][r] = val ? w3v[nf] * sp : 0.f;
      }
    }
#pragma unroll
  for (int off = 32; off > 0; off >>= 1) epart += __shfl_down(epart, off, 64);
  if (lane == 0) atomicAdd(&blockE, epart);

  __syncthreads();  // all reads of h1 done
#pragma unroll
  for (int mf = 0; mf < 4; ++mf)
#pragma unroll
    for (int nf = 0; nf < 4; ++nf)
#pragma unroll
      for (int r = 0; r < 4; ++r)
        bufA[swz(mf * 16 + q * 4 + r, n0 + nf * 16 + lm)] = f2bf(acc[mf][nf][r]);
  __syncthreads();
  if (tid == 0) atomicAdd(out, blockE + (float)vcnt * b3p[0]);

  // ---- phase 3: backward GEMM dH1 = dz2 @ W2^T ----
#pragma unroll
  for (int mf = 0; mf < 4; ++mf)
#pragma unroll
    for (int nf = 0; nf < 4; ++nf) acc[mf][nf] = (f32x4){0.f, 0.f, 0.f, 0.f};

#pragma unroll 4
  for (int kk = 0; kk < 16; ++kk) {
    short8 a[4];
#pragma unroll
    for (int mf = 0; mf < 4; ++mf)
      a[mf] = *(const short8*)&bufA[swz(mf * 16 + lm, kk * 32 + q * 8)];
#pragma unroll
    for (int nf = 0; nf < 4; ++nf) {
      short8 bfr = *(const short8*)(Wb + ((((w * 4 + nf) * 16 + kk) * 64 + lane) << 3));
#pragma unroll
      for (int mf = 0; mf < 4; ++mf)
        acc[mf][nf] = __builtin_amdgcn_mfma_f32_16x16x32_bf16(a[mf], bfr, acc[mf][nf], 0, 0, 0);
    }
  }

  // ---- phase 4: dz1 = dH1 * silu'(z1); z1 via bf16 re-MFMA (per-nf slice) ----
#pragma unroll
  for (int nf = 0; nf < 4; ++nf) {
    const int col = n0 + nf * 16 + lm;
    short8 Bh;
#pragma unroll
    for (int j = 0; j < 8; ++j) {
      int k = q * 8 + j;
      Bh[j] = (short)f2bf((k < IN) ? W1[k * HDIM + col] : 0.f);
    }
    f32x4 zacc[4];
#pragma unroll
    for (int mf = 0; mf < 4; ++mf) zacc[mf] = (f32x4){0.f, 0.f, 0.f, 0.f};
#pragma unroll
    for (int mf = 0; mf < 4; ++mf)
      zacc[mf] = __builtin_amdgcn_mfma_f32_16x16x32_bf16(Ah[mf], Bh, zacc[mf], 0, 0, 0);
#pragma unroll
    for (int mf = 0; mf < 4; ++mf)
#pragma unroll
      for (int r = 0; r < 4; ++r) {
        float z = zacc[mf][r] + b1v[nf];
        float s = 1.f / (1.f + __expf(-z));
        float sp = s * (1.f + z * (1.f - s));
        acc[mf][nf][r] *= sp;
      }
  }
  __syncthreads();  // all reads of dz2 done
#pragma unroll
  for (int mf = 0; mf < 4; ++mf)
#pragma unroll
    for (int nf = 0; nf < 4; ++nf)
#pragma unroll
      for (int r = 0; r < 4; ++r)
        bufA[swz(mf * 16 + q * 4 + r, n0 + nf * 16 + lm)] = f2bf(acc[mf][nf][r]);
  __syncthreads();

  // ---- phase 5: dh0 = dz1 @ W1^T via MFMA, K split across 8 waves ----
  {
    f32x4 pacc[4];
#pragma unroll
    for (int mf = 0; mf < 4; ++mf) pacc[mf] = (f32x4){0.f, 0.f, 0.f, 0.f};
    const int ncol = (lm < GD) ? lm : 0;  // B row clamp; cols >= GD discarded
#pragma unroll
    for (int t = 0; t < 2; ++t) {
      int kk = w * 2 + t;
      short8 b = *(const short8*)&W1s[ncol * HDIM + kk * 32 + q * 8];
      short8 a[4];
#pragma unroll
      for (int mf = 0; mf < 4; ++mf)
        a[mf] = *(const short8*)&bufA[swz(mf * 16 + lm, kk * 32 + q * 8)];
#pragma unroll
      for (int mf = 0; mf < 4; ++mf)
        pacc[mf] = __builtin_amdgcn_mfma_f32_16x16x32_bf16(a[mf], b, pacc[mf], 0, 0, 0);
    }
    if (lm < GD) {
#pragma unroll
      for (int mf = 0; mf < 4; ++mf)
#pragma unroll
        for (int r = 0; r < 4; ++r)
          atomicAdd(&dh0s[mf * 16 + q * 4 + r][lm], pacc[mf][r]);
    }
  }
  __syncthreads();

  // ---- scatter grads ----
  {
    int e = tid >> 3, k7 = tid & 7;
    if (k7 < GD && e < vcnt) {
      int obj = k7 >> 1, d = k7 & 1;
      atomicAdd(&out[1 + idxs[e * ARITY + obj] * 2 + d], dh0s[e][k7]);
    }
  }
}

extern "C" void kernel_launch(void* const* d_in, const int* in_sizes, int n_in,
                              void* d_out, int out_size, void* d_ws, size_t ws_size,
                              hipStream_t stream) {
  const float* x    = (const float*)d_in[0];
  const float* sig  = (const float*)d_in[1];
  const int*   ep   = (const int*)d_in[2];
  const int*   et   = (const int*)d_in[3];
  const float* pW1  = (const float*)d_in[4];
  const float* pb1  = (const float*)d_in[5];
  const float* pW2  = (const float*)d_in[6];
  const float* pb2  = (const float*)d_in[7];
  const float* pW3  = (const float*)d_in[8];
  const float* pb3  = (const float*)d_in[9];
  const float* tW1  = (const float*)d_in[10];
  const float* tb1  = (const float*)d_in[11];
  const float* tW2  = (const float*)d_in[12];
  const float* tb2  = (const float*)d_in[13];
  const float* tW3  = (const float*)d_in[14];
  const float* tb3  = (const float*)d_in[15];
  const int E2 = in_sizes[2] / 2;
  const int E3 = in_sizes[3] / 3;
  float* out = (float*)d_out;

  unsigned short* pWf = (unsigned short*)d_ws;
  unsigned short* pWb = pWf + HDIM * HDIM;
  unsigned short* tWf = pWb + HDIM * HDIM;
  unsigned short* tWb = tWf + HDIM * HDIM;

  hipMemsetAsync(d_out, 0, (size_t)out_size * sizeof(float), stream);
  prep_weights<<<(HDIM * HDIM + 255) / 256, 256, 0, stream>>>(pW2, tW2, pWf, pWb, tWf, tWb);
  energy_kernel<2><<<(E2 + TILE - 1) / TILE, TPB, 0, stream>>>(
      x, sig, ep, E2, pW1, pb1, pWf, pWb, pb2, pW3, pb3, out);
  energy_kernel<3><<<(E3 + TILE - 1) / TILE, TPB, 0, stream>>>(
      x, sig, et, E3, tW1, tb1, tWf, tWb, tb2, tW3, tb3, out);
}

// Round 3
// 658.843 us; speedup vs baseline: 1.9830x; 1.9830x over previous
//
#include <hip/hip_runtime.h>
#include <hip/hip_bf16.h>

#define HDIM 512
#define TILE 64
#define TPB 512

typedef __attribute__((ext_vector_type(8))) short short8;
typedef __attribute__((ext_vector_type(4))) float f32x4;

__device__ __forceinline__ unsigned short f2bf(float x) {
  __hip_bfloat16 h = __float2bfloat16(x);
  return *reinterpret_cast<unsigned short*>(&h);
}
__device__ __forceinline__ float bf2f(unsigned short h) {
  return __uint_as_float(((unsigned)h) << 16);
}
// XOR-swizzled ushort index into [row][col] bf16 tile, row stride 512 elems.
// xb = ((row&12)>>1)|(row&1): b128 frag reads (16 rows/quarter) spread over
// 8 distinct 16B slots (2-way = free); b16 epilogue stores put the quarter
// index into bank bits [4:3] -> 32 banks x 2 lanes = free.
__device__ __forceinline__ int swz(int row, int col) {
  int xb = ((row & 12) >> 1) | (row & 1);
  return (((row << 10) + (col << 1)) ^ (xb << 4)) >> 1;
}

// W2 (512x512 f32 [k][n]) -> bf16 MFMA-fragment-major, fwd B[k][n] and bwd B[n][k].
__global__ void prep_weights(const float* __restrict__ pW2, const float* __restrict__ tW2,
                             unsigned short* __restrict__ pWf, unsigned short* __restrict__ pWb,
                             unsigned short* __restrict__ tWf, unsigned short* __restrict__ tWb) {
  int i = blockIdx.x * blockDim.x + threadIdx.x;
  if (i >= HDIM * HDIM) return;
  int j  = i & 7;
  int l  = (i >> 3) & 63;
  int kb = (i >> 9) & 15;
  int nb = i >> 13;
  int kpos = kb * 32 + ((l >> 4) << 3) + j;
  int npos = nb * 16 + (l & 15);
  pWf[i] = f2bf(pW2[kpos * HDIM + npos]);
  pWb[i] = f2bf(pW2[npos * HDIM + kpos]);
  tWf[i] = f2bf(tW2[kpos * HDIM + npos]);
  tWb[i] = f2bf(tW2[npos * HDIM + kpos]);
}

template <int ARITY>
__global__ void __launch_bounds__(TPB, 2)
energy_kernel(const float* __restrict__ x, const float* __restrict__ sigp,
              const int* __restrict__ edges, int Etot,
              const float* __restrict__ W1, const float* __restrict__ b1,
              const unsigned short* __restrict__ Wf, const unsigned short* __restrict__ Wb,
              const float* __restrict__ b2, const float* __restrict__ w3,
              const float* __restrict__ b3p, float* __restrict__ out) {
  constexpr int IN = 3 * ARITY;   // arity*dim + arity
  constexpr int GD = 2 * ARITY;   // grad components per edge
  __shared__ __align__(16) unsigned short bufA[TILE * HDIM];  // h1 -> dz2 -> dz1
  __shared__ __align__(16) unsigned short W1s[GD * HDIM];     // bf16 W1 rows 0..GD-1 (phase-5 B)
  __shared__ __align__(16) float h0s[TILE][16];
  __shared__ float dh0s[TILE][8];
  __shared__ int   idxs[TILE * ARITY];
  __shared__ float blockE;

  const int tid  = threadIdx.x;
  const int lane = tid & 63;
  const int w    = tid >> 6;
  const int q    = lane >> 4;
  const int lm   = lane & 15;
  const int tile0 = blockIdx.x * TILE;
  const int vcnt  = min(TILE, Etot - tile0);
  const float sigma = sigp[0];

  // ---- phase 0: init ----
  if (tid == 0) blockE = 0.f;
  ((float*)dh0s)[tid] = 0.f;                       // 64*8 == TPB
  if (tid < TILE * ARITY) {
    int e = tid / ARITY;
    idxs[tid] = (e < vcnt) ? edges[(size_t)tile0 * ARITY + tid] : 0;
  }
  for (int i = tid; i < GD * HDIM; i += TPB) W1s[i] = f2bf(W1[i]);
  __syncthreads();
  if (tid < TILE) {
#pragma unroll
    for (int k = 0; k < 16; ++k) h0s[tid][k] = 0.f;
    if (tid < vcnt) {
#pragma unroll
      for (int o = 0; o < ARITY; ++o) {
        int id = idxs[tid * ARITY + o];
        h0s[tid][o * 2 + 0] = x[id * 2 + 0];
        h0s[tid][o * 2 + 1] = x[id * 2 + 1];
        h0s[tid][ARITY * 2 + o] = sigma;
      }
    }
  }
  __syncthreads();

  const int n0 = w * 64;

  // ---- phase 1: layer 1 via split-bf16 MFMA ----
  // A-fragments of h0 (hi/lo), Ah kept live for phase-4 re-MFMA.
  short8 Ah[4], Al[4];
#pragma unroll
  for (int mf = 0; mf < 4; ++mf) {
    f32x4 v0 = {0.f, 0.f, 0.f, 0.f}, v1 = {0.f, 0.f, 0.f, 0.f};
    if (q < 2) {
      const float* p = &h0s[mf * 16 + lm][q * 8];
      v0 = *(const f32x4*)p;
      v1 = *(const f32x4*)(p + 4);
    }
#pragma unroll
    for (int j = 0; j < 4; ++j) {
      unsigned short ha = f2bf(v0[j]);
      Ah[mf][j] = (short)ha;
      Al[mf][j] = (short)f2bf(v0[j] - bf2f(ha));
      unsigned short hb = f2bf(v1[j]);
      Ah[mf][j + 4] = (short)hb;
      Al[mf][j + 4] = (short)f2bf(v1[j] - bf2f(hb));
    }
  }

  f32x4 acc[4][4];
#pragma unroll
  for (int mf = 0; mf < 4; ++mf)
#pragma unroll
    for (int nf = 0; nf < 4; ++nf) acc[mf][nf] = (f32x4){0.f, 0.f, 0.f, 0.f};

  float b1v[4];
#pragma unroll
  for (int nf = 0; nf < 4; ++nf) {
    const int col = n0 + nf * 16 + lm;
    b1v[nf] = b1[col];
    short8 Bh, Bl;
#pragma unroll
    for (int j = 0; j < 8; ++j) {
      int k = q * 8 + j;
      float v = (k < IN) ? W1[k * HDIM + col] : 0.f;
      unsigned short hb = f2bf(v);
      Bh[j] = (short)hb;
      Bl[j] = (short)f2bf(v - bf2f(hb));
    }
#pragma unroll
    for (int mf = 0; mf < 4; ++mf) {
      acc[mf][nf] = __builtin_amdgcn_mfma_f32_16x16x32_bf16(Ah[mf], Bh, acc[mf][nf], 0, 0, 0);
      acc[mf][nf] = __builtin_amdgcn_mfma_f32_16x16x32_bf16(Al[mf], Bh, acc[mf][nf], 0, 0, 0);
      acc[mf][nf] = __builtin_amdgcn_mfma_f32_16x16x32_bf16(Ah[mf], Bl, acc[mf][nf], 0, 0, 0);
    }
  }

  // silu(z1) -> bufA (bf16)
#pragma unroll
  for (int mf = 0; mf < 4; ++mf)
#pragma unroll
    for (int nf = 0; nf < 4; ++nf)
#pragma unroll
      for (int r = 0; r < 4; ++r) {
        int row = mf * 16 + q * 4 + r;
        float z = acc[mf][nf][r] + b1v[nf];
        float s = 1.f / (1.f + __expf(-z));
        float hv = (row < vcnt) ? z * s : 0.f;
        bufA[swz(row, n0 + nf * 16 + lm)] = f2bf(hv);
      }
  __syncthreads();

  float b2v[4], w3v[4];
#pragma unroll
  for (int nf = 0; nf < 4; ++nf) {
    b2v[nf] = b2[n0 + nf * 16 + lm];
    w3v[nf] = w3[n0 + nf * 16 + lm];
  }

  // ---- phase 2: forward GEMM z2 = h1 @ W2 ----
#pragma unroll
  for (int mf = 0; mf < 4; ++mf)
#pragma unroll
    for (int nf = 0; nf < 4; ++nf) acc[mf][nf] = (f32x4){0.f, 0.f, 0.f, 0.f};

#pragma unroll 4
  for (int kk = 0; kk < 16; ++kk) {
    short8 a[4];
#pragma unroll
    for (int mf = 0; mf < 4; ++mf)
      a[mf] = *(const short8*)&bufA[swz(mf * 16 + lm, kk * 32 + q * 8)];
#pragma unroll
    for (int nf = 0; nf < 4; ++nf) {
      short8 bfr = *(const short8*)(Wf + ((((w * 4 + nf) * 16 + kk) * 64 + lane) << 3));
#pragma unroll
      for (int mf = 0; mf < 4; ++mf)
        acc[mf][nf] = __builtin_amdgcn_mfma_f32_16x16x32_bf16(a[mf], bfr, acc[mf][nf], 0, 0, 0);
    }
  }

  // ---- epilogue fwd: energy + dz2 = w3*silu'(z2) ----
  float epart = 0.f;
#pragma unroll
  for (int mf = 0; mf < 4; ++mf)
#pragma unroll
    for (int r = 0; r < 4; ++r) {
      int row = mf * 16 + q * 4 + r;
      bool val = row < vcnt;
#pragma unroll
      for (int nf = 0; nf < 4; ++nf) {
        float z = acc[mf][nf][r] + b2v[nf];
        float s = 1.f / (1.f + __expf(-z));
        float h2 = z * s;
        float sp = s * (1.f + z * (1.f - s));
        epart += val ? h2 * w3v[nf] : 0.f;
        acc[mf][nf][r] = val ? w3v[nf] * sp : 0.f;
      }
    }
#pragma unroll
  for (int off = 32; off > 0; off >>= 1) epart += __shfl_down(epart, off, 64);
  if (lane == 0) atomicAdd(&blockE, epart);

  __syncthreads();  // all reads of h1 done
#pragma unroll
  for (int mf = 0; mf < 4; ++mf)
#pragma unroll
    for (int nf = 0; nf < 4; ++nf)
#pragma unroll
      for (int r = 0; r < 4; ++r)
        bufA[swz(mf * 16 + q * 4 + r, n0 + nf * 16 + lm)] = f2bf(acc[mf][nf][r]);
  __syncthreads();
  if (tid == 0) atomicAdd(out, blockE + (float)vcnt * b3p[0]);

  // ---- phase 3: backward GEMM dH1 = dz2 @ W2^T ----
#pragma unroll
  for (int mf = 0; mf < 4; ++mf)
#pragma unroll
    for (int nf = 0; nf < 4; ++nf) acc[mf][nf] = (f32x4){0.f, 0.f, 0.f, 0.f};

#pragma unroll 4
  for (int kk = 0; kk < 16; ++kk) {
    short8 a[4];
#pragma unroll
    for (int mf = 0; mf < 4; ++mf)
      a[mf] = *(const short8*)&bufA[swz(mf * 16 + lm, kk * 32 + q * 8)];
#pragma unroll
    for (int nf = 0; nf < 4; ++nf) {
      short8 bfr = *(const short8*)(Wb + ((((w * 4 + nf) * 16 + kk) * 64 + lane) << 3));
#pragma unroll
      for (int mf = 0; mf < 4; ++mf)
        acc[mf][nf] = __builtin_amdgcn_mfma_f32_16x16x32_bf16(a[mf], bfr, acc[mf][nf], 0, 0, 0);
    }
  }

  // ---- phase 4: dz1 = dH1 * silu'(z1); z1 via bf16 re-MFMA (per-nf slice) ----
#pragma unroll
  for (int nf = 0; nf < 4; ++nf) {
    const int col = n0 + nf * 16 + lm;
    short8 Bh;
#pragma unroll
    for (int j = 0; j < 8; ++j) {
      int k = q * 8 + j;
      Bh[j] = (short)f2bf((k < IN) ? W1[k * HDIM + col] : 0.f);
    }
    f32x4 zacc[4];
#pragma unroll
    for (int mf = 0; mf < 4; ++mf) zacc[mf] = (f32x4){0.f, 0.f, 0.f, 0.f};
#pragma unroll
    for (int mf = 0; mf < 4; ++mf)
      zacc[mf] = __builtin_amdgcn_mfma_f32_16x16x32_bf16(Ah[mf], Bh, zacc[mf], 0, 0, 0);
#pragma unroll
    for (int mf = 0; mf < 4; ++mf)
#pragma unroll
      for (int r = 0; r < 4; ++r) {
        float z = zacc[mf][r] + b1v[nf];
        float s = 1.f / (1.f + __expf(-z));
        float sp = s * (1.f + z * (1.f - s));
        acc[mf][nf][r] *= sp;
      }
  }
  __syncthreads();  // all reads of dz2 done
#pragma unroll
  for (int mf = 0; mf < 4; ++mf)
#pragma unroll
    for (int nf = 0; nf < 4; ++nf)
#pragma unroll
      for (int r = 0; r < 4; ++r)
        bufA[swz(mf * 16 + q * 4 + r, n0 + nf * 16 + lm)] = f2bf(acc[mf][nf][r]);
  __syncthreads();

  // ---- phase 5: dh0 = dz1 @ W1^T via MFMA, K split across 8 waves ----
  {
    f32x4 pacc[4];
#pragma unroll
    for (int mf = 0; mf < 4; ++mf) pacc[mf] = (f32x4){0.f, 0.f, 0.f, 0.f};
    const int ncol = (lm < GD) ? lm : 0;  // B row clamp; cols >= GD discarded
#pragma unroll
    for (int t = 0; t < 2; ++t) {
      int kk = w * 2 + t;
      short8 b = *(const short8*)&W1s[ncol * HDIM + kk * 32 + q * 8];
      short8 a[4];
#pragma unroll
      for (int mf = 0; mf < 4; ++mf)
        a[mf] = *(const short8*)&bufA[swz(mf * 16 + lm, kk * 32 + q * 8)];
#pragma unroll
      for (int mf = 0; mf < 4; ++mf)
        pacc[mf] = __builtin_amdgcn_mfma_f32_16x16x32_bf16(a[mf], b, pacc[mf], 0, 0, 0);
    }
    if (lm < GD) {
#pragma unroll
      for (int mf = 0; mf < 4; ++mf)
#pragma unroll
        for (int r = 0; r < 4; ++r)
          atomicAdd(&dh0s[mf * 16 + q * 4 + r][lm], pacc[mf][r]);
    }
  }
  __syncthreads();

  // ---- scatter grads ----
  {
    int e = tid >> 3, k7 = tid & 7;
    if (k7 < GD && e < vcnt) {
      int obj = k7 >> 1, d = k7 & 1;
      atomicAdd(&out[1 + idxs[e * ARITY + obj] * 2 + d], dh0s[e][k7]);
    }
  }
}

extern "C" void kernel_launch(void* const* d_in, const int* in_sizes, int n_in,
                              void* d_out, int out_size, void* d_ws, size_t ws_size,
                              hipStream_t stream) {
  const float* x    = (const float*)d_in[0];
  const float* sig  = (const float*)d_in[1];
  const int*   ep   = (const int*)d_in[2];
  const int*   et   = (const int*)d_in[3];
  const float* pW1  = (const float*)d_in[4];
  const float* pb1  = (const float*)d_in[5];
  const float* pW2  = (const float*)d_in[6];
  const float* pb2  = (const float*)d_in[7];
  const float* pW3  = (const float*)d_in[8];
  const float* pb3  = (const float*)d_in[9];
  const float* tW1  = (const float*)d_in[10];
  const float* tb1  = (const float*)d_in[11];
  const float* tW2  = (const float*)d_in[12];
  const float* tb2  = (const float*)d_in[13];
  const float* tW3  = (const float*)d_in[14];
  const float* tb3  = (const float*)d_in[15];
  const int E2 = in_sizes[2] / 2;
  const int E3 = in_sizes[3] / 3;
  float* out = (float*)d_out;

  unsigned short* pWf = (unsigned short*)d_ws;
  unsigned short* pWb = pWf + HDIM * HDIM;
  unsigned short* tWf = pWb + HDIM * HDIM;
  unsigned short* tWb = tWf + HDIM * HDIM;

  hipMemsetAsync(d_out, 0, (size_t)out_size * sizeof(float), stream);
  prep_weights<<<(HDIM * HDIM + 255) / 256, 256, 0, stream>>>(pW2, tW2, pWf, pWb, tWf, tWb);
  energy_kernel<2><<<(E2 + TILE - 1) / TILE, TPB, 0, stream>>>(
      x, sig, ep, E2, pW1, pb1, pWf, pWb, pb2, pW3, pb3, out);
  energy_kernel<3><<<(E3 + TILE - 1) / TILE, TPB, 0, stream>>>(
      x, sig, et, E3, tW1, tb1, tWf, tWb, tb2, tW3, tb3, out);
}